// Round 1
// baseline (101.519 us; speedup 1.0000x reference)
//
#include <hip/hip_runtime.h>
#include <hip/hip_fp16.h>

typedef _Float16 half8 __attribute__((ext_vector_type(8)));
typedef float f32x4 __attribute__((ext_vector_type(4)));

#define B_   8192
#define DIN  2048
#define C_   1000
#define CP   1024
#define NP2  512   // u,v interleaved rows

// ---- workspace layout (bytes) ----
static const size_t OFF_XH  = 0;                                   // xh  [8192][2048] f16
static const size_t OFF_WH  = OFF_XH  + (size_t)B_ * DIN * 2;      // wh  [1024][2048] f16 (rows>=1000 zero)
static const size_t OFF_UVH = OFF_WH  + (size_t)CP * DIN * 2;      // uvh [512][1024]  f16 (row 2q=u_q, 2q+1=v_q)
static const size_t OFF_PH  = OFF_UVH + (size_t)NP2 * CP * 2;      // predsh [8192][1024] f16
static const size_t OFF_SC  = OFF_PH  + (size_t)B_ * CP * 2;       // scores [8192] f32
static const size_t OFF_RS  = OFF_SC  + (size_t)B_ * 4;            // rowsum [8192] f32
static const size_t WS_NEED = OFF_RS  + (size_t)B_ * 4;

__device__ __forceinline__ void gload16(const void* g, void* l) {
  __builtin_amdgcn_global_load_lds(
      (const __attribute__((address_space(1))) void*)g,
      (__attribute__((address_space(3))) void*)l, 16, 0, 0);
}

// ---------------- prep: f32 -> f16 conversions + zeroing ----------------
__global__ __launch_bounds__(256) void prep_kernel(
    const float* __restrict__ x, const float* __restrict__ Wm,
    const float* __restrict__ u, const float* __restrict__ v,
    _Float16* __restrict__ xh, _Float16* __restrict__ wh,
    _Float16* __restrict__ uvh, float* __restrict__ scores,
    float* __restrict__ rowsum)
{
  const long NX  = (long)B_ * DIN / 8;      // 2,097,152
  const long NW  = (long)CP * DIN / 8;      //   262,144
  const long NUV = (long)NP2 * CP / 8;      //    65,536
  const long NZ  = 2 * (long)B_ / 8;        //     2,048
  const long T   = NX + NW + NUV + NZ;
  for (long idx = (long)blockIdx.x * blockDim.x + threadIdx.x; idx < T;
       idx += (long)gridDim.x * blockDim.x) {
    if (idx < NX) {
      long e = idx * 8;
      float4 p0 = *(const float4*)(x + e);
      float4 p1 = *(const float4*)(x + e + 4);
      half8 h;
      h[0] = (_Float16)p0.x; h[1] = (_Float16)p0.y; h[2] = (_Float16)p0.z; h[3] = (_Float16)p0.w;
      h[4] = (_Float16)p1.x; h[5] = (_Float16)p1.y; h[6] = (_Float16)p1.z; h[7] = (_Float16)p1.w;
      *(half8*)(xh + e) = h;
    } else if (idx < NX + NW) {
      long e = (idx - NX) * 8;
      int row = (int)(e >> 11);
      half8 h;
      if (row < C_) {
        float4 p0 = *(const float4*)(Wm + e);
        float4 p1 = *(const float4*)(Wm + e + 4);
        h[0] = (_Float16)p0.x; h[1] = (_Float16)p0.y; h[2] = (_Float16)p0.z; h[3] = (_Float16)p0.w;
        h[4] = (_Float16)p1.x; h[5] = (_Float16)p1.y; h[6] = (_Float16)p1.z; h[7] = (_Float16)p1.w;
      } else {
        h = (half8)(_Float16)0.f;
      }
      *(half8*)(wh + e) = h;
    } else if (idx < NX + NW + NUV) {
      long e = (idx - NX - NW) * 8;
      int j = (int)(e >> 10);
      int k = (int)(e & 1023);
      const float* src = (j & 1) ? v : u;
      int p = j >> 1;
      half8 h;
      #pragma unroll
      for (int t = 0; t < 8; ++t) {
        int kk = k + t;
        h[t] = (kk < C_) ? (_Float16)src[(size_t)p * C_ + kk] : (_Float16)0.f;
      }
      *(half8*)(uvh + e) = h;
    } else {
      long e = (idx - NX - NW - NUV) * 8;
      float4 z = {0.f, 0.f, 0.f, 0.f};
      if (e < B_) {
        *(float4*)(scores + e) = z; *(float4*)(scores + e + 4) = z;
      } else {
        long r = e - B_;
        *(float4*)(rowsum + r) = z; *(float4*)(rowsum + r + 4) = z;
      }
    }
  }
}

// ---------------- main GEMM: preds = xh @ wh^T + bm ----------------
__global__ __launch_bounds__(256) void gemm1_kernel(
    const _Float16* __restrict__ xh, const _Float16* __restrict__ wh,
    const float* __restrict__ bmv, float* __restrict__ preds,
    _Float16* __restrict__ predsh, float* __restrict__ rowsum)
{
  __shared__ _Float16 sA[128 * 64];
  __shared__ _Float16 sB[128 * 64];
  const int tid  = threadIdx.x;
  const int lane = tid & 63;
  const int w    = tid >> 6;
  const int wm   = w >> 1, wn = w & 1;
  const int bm0  = blockIdx.x * 128;
  const int bn0  = blockIdx.y * 128;

  f32x4 acc[4][4] = {};

  const _Float16* srcA[4]; const _Float16* srcB[4];
  _Float16* dstA[4]; _Float16* dstB[4];
  #pragma unroll
  for (int i = 0; i < 4; ++i) {
    int slot = i * 256 + tid;
    int row  = slot >> 3;
    int cb   = (slot & 7) << 4;
    int scb  = cb ^ ((row & 7) << 4);                 // inverse-swizzled source
    srcA[i] = xh + (size_t)(bm0 + row) * DIN + (scb >> 1);
    srcB[i] = wh + (size_t)(bn0 + row) * DIN + (scb >> 1);
    dstA[i] = sA + (i * 4 + w) * 512;                 // wave-uniform base, lane*16B appended by HW
    dstB[i] = sB + (i * 4 + w) * 512;
  }
  int aoff[4][2], boff[4][2];
  #pragma unroll
  for (int mi = 0; mi < 4; ++mi) {
    #pragma unroll
    for (int ks = 0; ks < 2; ++ks) {
      int kb = ks * 64 + (lane >> 4) * 16;
      int ra = wm * 64 + mi * 16 + (lane & 15);
      aoff[mi][ks] = ra * 128 + (kb ^ ((ra & 7) << 4));
      int rb = wn * 64 + mi * 16 + (lane & 15);
      boff[mi][ks] = rb * 128 + (kb ^ ((rb & 7) << 4));
    }
  }

  for (int kt = 0; kt < DIN / 64; ++kt) {
    #pragma unroll
    for (int i = 0; i < 4; ++i) {
      gload16(srcA[i], dstA[i]);
      gload16(srcB[i], dstB[i]);
      srcA[i] += 64; srcB[i] += 64;
    }
    asm volatile("s_waitcnt vmcnt(0)" ::: "memory");
    __syncthreads();
    #pragma unroll
    for (int ks = 0; ks < 2; ++ks) {
      half8 a[4], b[4];
      #pragma unroll
      for (int mi = 0; mi < 4; ++mi) a[mi] = *(const half8*)((const char*)sA + aoff[mi][ks]);
      #pragma unroll
      for (int ni = 0; ni < 4; ++ni) b[ni] = *(const half8*)((const char*)sB + boff[ni][ks]);
      #pragma unroll
      for (int mi = 0; mi < 4; ++mi)
        #pragma unroll
        for (int ni = 0; ni < 4; ++ni)
          acc[mi][ni] = __builtin_amdgcn_mfma_f32_16x16x32_f16(a[mi], b[ni], acc[mi][ni], 0, 0, 0);
    }
    __syncthreads();
  }

  // epilogue: bias add, f32 store to d_out, f16 store for gating, rowsum partials
  float rp[4][4] = {};
  #pragma unroll
  for (int mi = 0; mi < 4; ++mi) {
    #pragma unroll
    for (int ni = 0; ni < 4; ++ni) {
      f32x4 d = acc[mi][ni];
      int gc = bn0 + wn * 64 + ni * 16 + (lane & 15);
      float bias = (gc < C_) ? bmv[gc] : 0.f;
      #pragma unroll
      for (int j = 0; j < 4; ++j) {
        int gr = bm0 + wm * 64 + mi * 16 + (lane >> 4) * 4 + j;
        float val = d[j] + bias;
        predsh[(size_t)gr * CP + gc] = (_Float16)val;
        if (gc < C_) preds[(size_t)gr * C_ + gc] = val;
        rp[mi][j] += val;
      }
    }
  }
  #pragma unroll
  for (int mi = 0; mi < 4; ++mi) {
    #pragma unroll
    for (int j = 0; j < 4; ++j) {
      float s = rp[mi][j];
      s += __shfl_xor(s, 1); s += __shfl_xor(s, 2);
      s += __shfl_xor(s, 4); s += __shfl_xor(s, 8);
      if ((lane & 15) == 0) {
        int gr = bm0 + wm * 64 + mi * 16 + (lane >> 4) * 4 + j;
        atomicAdd(&rowsum[gr], s);
      }
    }
  }
}

// ---------------- gating GEMM: scores partials ----------------
__global__ __launch_bounds__(256) void gemm2_kernel(
    const _Float16* __restrict__ predsh, const _Float16* __restrict__ uvh,
    const float* __restrict__ wv, float* __restrict__ scores)
{
  __shared__ _Float16 sA[128 * 64];
  __shared__ _Float16 sB[128 * 64];
  const int tid  = threadIdx.x;
  const int lane = tid & 63;
  const int w    = tid >> 6;
  const int wm   = w >> 1, wn = w & 1;
  const int bm0  = blockIdx.x * 128;
  const int bn0  = blockIdx.y * 128;

  f32x4 acc[4][4] = {};

  const _Float16* srcA[4]; const _Float16* srcB[4];
  _Float16* dstA[4]; _Float16* dstB[4];
  #pragma unroll
  for (int i = 0; i < 4; ++i) {
    int slot = i * 256 + tid;
    int row  = slot >> 3;
    int cb   = (slot & 7) << 4;
    int scb  = cb ^ ((row & 7) << 4);
    srcA[i] = predsh + (size_t)(bm0 + row) * CP + (scb >> 1);
    srcB[i] = uvh    + (size_t)(bn0 + row) * CP + (scb >> 1);
    dstA[i] = sA + (i * 4 + w) * 512;
    dstB[i] = sB + (i * 4 + w) * 512;
  }
  int aoff[4][2], boff[4][2];
  #pragma unroll
  for (int mi = 0; mi < 4; ++mi) {
    #pragma unroll
    for (int ks = 0; ks < 2; ++ks) {
      int kb = ks * 64 + (lane >> 4) * 16;
      int ra = wm * 64 + mi * 16 + (lane & 15);
      aoff[mi][ks] = ra * 128 + (kb ^ ((ra & 7) << 4));
      int rb = wn * 64 + mi * 16 + (lane & 15);
      boff[mi][ks] = rb * 128 + (kb ^ ((rb & 7) << 4));
    }
  }

  for (int kt = 0; kt < CP / 64; ++kt) {
    #pragma unroll
    for (int i = 0; i < 4; ++i) {
      gload16(srcA[i], dstA[i]);
      gload16(srcB[i], dstB[i]);
      srcA[i] += 64; srcB[i] += 64;
    }
    asm volatile("s_waitcnt vmcnt(0)" ::: "memory");
    __syncthreads();
    #pragma unroll
    for (int ks = 0; ks < 2; ++ks) {
      half8 a[4], b[4];
      #pragma unroll
      for (int mi = 0; mi < 4; ++mi) a[mi] = *(const half8*)((const char*)sA + aoff[mi][ks]);
      #pragma unroll
      for (int ni = 0; ni < 4; ++ni) b[ni] = *(const half8*)((const char*)sB + boff[ni][ks]);
      #pragma unroll
      for (int mi = 0; mi < 4; ++mi)
        #pragma unroll
        for (int ni = 0; ni < 4; ++ni)
          acc[mi][ni] = __builtin_amdgcn_mfma_f32_16x16x32_f16(a[mi], b[ni], acc[mi][ni], 0, 0, 0);
    }
    __syncthreads();
  }

  // epilogue: gated = tanh(e_u)*sigmoid(e_v)*w_q ; accumulate per-row score partials
  float sp[4][4] = {};
  #pragma unroll
  for (int mi = 0; mi < 4; ++mi) {
    #pragma unroll
    for (int ni = 0; ni < 4; ++ni) {
      f32x4 d = acc[mi][ni];
      int gc = bn0 + wn * 64 + ni * 16 + (lane & 15);   // 0..511 ; even=u col, odd=v col
      float wq = wv[gc >> 1];
      bool even = ((gc & 1) == 0);
      #pragma unroll
      for (int j = 0; j < 4; ++j) {
        float t  = d[j];
        float pr = __shfl_xor(t, 1);                    // partner column value
        float th = 2.f / (1.f + __expf(-2.f * t)) - 1.f; // tanh
        float sg = 1.f / (1.f + __expf(-pr));            // sigmoid
        sp[mi][j] += even ? (th * sg * wq) : 0.f;
      }
    }
  }
  #pragma unroll
  for (int mi = 0; mi < 4; ++mi) {
    #pragma unroll
    for (int j = 0; j < 4; ++j) {
      float s = sp[mi][j];
      s += __shfl_xor(s, 1); s += __shfl_xor(s, 2);
      s += __shfl_xor(s, 4); s += __shfl_xor(s, 8);
      if ((lane & 15) == 0) {
        int gr = bm0 + wm * 64 + mi * 16 + (lane >> 4) * 4 + j;
        atomicAdd(&scores[gr], s);
      }
    }
  }
}

// ---------------- final: softmax over scores, weighted rowsum ----------------
__global__ __launch_bounds__(1024) void final_kernel(
    const float* __restrict__ scores, const float* __restrict__ rowsum,
    float* __restrict__ out)
{
  __shared__ float red[16], red2[16];
  const int t = threadIdx.x;
  const int lane = t & 63, wid = t >> 6;
  float s[8];
  float m = -3.4e38f;
  #pragma unroll
  for (int i = 0; i < 8; ++i) { s[i] = scores[t + i * 1024]; m = fmaxf(m, s[i]); }
  #pragma unroll
  for (int off = 1; off < 64; off <<= 1) m = fmaxf(m, __shfl_xor(m, off));
  if (lane == 0) red[wid] = m;
  __syncthreads();
  #pragma unroll
  for (int i = 0; i < 16; ++i) m = fmaxf(m, red[i]);
  __syncthreads();

  float se = 0.f, sr = 0.f;
  #pragma unroll
  for (int i = 0; i < 8; ++i) {
    float e = __expf(s[i] - m);
    se += e;
    sr += e * rowsum[t + i * 1024];
  }
  #pragma unroll
  for (int off = 1; off < 64; off <<= 1) { se += __shfl_xor(se, off); sr += __shfl_xor(sr, off); }
  if (lane == 0) { red[wid] = se; red2[wid] = sr; }
  __syncthreads();
  if (t == 0) {
    float tse = 0.f, tsr = 0.f;
    for (int i = 0; i < 16; ++i) { tse += red[i]; tsr += red2[i]; }
    out[0] = tsr / tse;
  }
}

extern "C" void kernel_launch(void* const* d_in, const int* in_sizes, int n_in,
                              void* d_out, int out_size, void* d_ws, size_t ws_size,
                              hipStream_t stream)
{
  const float* x   = (const float*)d_in[0];
  const float* Wm  = (const float*)d_in[1];
  const float* bmv = (const float*)d_in[2];
  const float* u   = (const float*)d_in[3];
  const float* v   = (const float*)d_in[4];
  const float* wv  = (const float*)d_in[5];
  float* out = (float*)d_out;

  if (ws_size < WS_NEED) return;  // fail loudly via validation rather than corrupt

  char* ws = (char*)d_ws;
  _Float16* xh     = (_Float16*)(ws + OFF_XH);
  _Float16* wh     = (_Float16*)(ws + OFF_WH);
  _Float16* uvh    = (_Float16*)(ws + OFF_UVH);
  _Float16* predsh = (_Float16*)(ws + OFF_PH);
  float*    scores = (float*)(ws + OFF_SC);
  float*    rowsum = (float*)(ws + OFF_RS);

  prep_kernel<<<2048, 256, 0, stream>>>(x, Wm, u, v, xh, wh, uvh, scores, rowsum);
  gemm1_kernel<<<dim3(64, 8), 256, 0, stream>>>(xh, wh, bmv, out, predsh, rowsum);
  gemm2_kernel<<<dim3(64, 4), 256, 0, stream>>>(predsh, uvh, wv, scores);
  final_kernel<<<1, 1024, 0, stream>>>(scores, rowsum, out + (size_t)B_ * C_);
}

// Round 2
// 95.595 us; speedup vs baseline: 1.0620x; 1.0620x over previous
//
#include <hip/hip_runtime.h>
#include <hip/hip_fp16.h>

typedef _Float16 half8 __attribute__((ext_vector_type(8)));
typedef float f32x4 __attribute__((ext_vector_type(4)));

#define B_   8192
#define DIN  2048
#define C_   1000
#define CP   1024
#define NP2  512   // u,v interleaved rows

// ---- workspace layout (bytes) ----
static const size_t OFF_XH  = 0;                                   // xh  [8192][2048] f16
static const size_t OFF_WH  = OFF_XH  + (size_t)B_ * DIN * 2;      // wh  [1024][2048] f16 (rows>=1000 zero)
static const size_t OFF_UVH = OFF_WH  + (size_t)CP * DIN * 2;      // uvh [512][1024]  f16 (row 2q=u_q, 2q+1=v_q)
static const size_t OFF_PH  = OFF_UVH + (size_t)NP2 * CP * 2;      // predsh [8192][1024] f16
static const size_t OFF_SC  = OFF_PH  + (size_t)B_ * CP * 2;       // scores [8192] f32
static const size_t OFF_RS  = OFF_SC  + (size_t)B_ * 4;            // rowsum [8192] f32
static const size_t WS_NEED = OFF_RS  + (size_t)B_ * 4;

__device__ __forceinline__ void gload16(const void* g, void* l) {
  __builtin_amdgcn_global_load_lds(
      (const __attribute__((address_space(1))) void*)g,
      (__attribute__((address_space(3))) void*)l, 16, 0, 0);
}

// ---------------- prep: f32 -> f16 conversions + zeroing ----------------
__global__ __launch_bounds__(256) void prep_kernel(
    const float* __restrict__ x, const float* __restrict__ Wm,
    const float* __restrict__ u, const float* __restrict__ v,
    _Float16* __restrict__ xh, _Float16* __restrict__ wh,
    _Float16* __restrict__ uvh, float* __restrict__ scores,
    float* __restrict__ rowsum)
{
  const long NX  = (long)B_ * DIN / 8;      // 2,097,152
  const long NW  = (long)CP * DIN / 8;      //   262,144
  const long NUV = (long)NP2 * CP / 8;      //    65,536
  const long NZ  = 2 * (long)B_ / 8;        //     2,048
  const long T   = NX + NW + NUV + NZ;
  for (long idx = (long)blockIdx.x * blockDim.x + threadIdx.x; idx < T;
       idx += (long)gridDim.x * blockDim.x) {
    if (idx < NX) {
      long e = idx * 8;
      float4 p0 = *(const float4*)(x + e);
      float4 p1 = *(const float4*)(x + e + 4);
      half8 h;
      h[0] = (_Float16)p0.x; h[1] = (_Float16)p0.y; h[2] = (_Float16)p0.z; h[3] = (_Float16)p0.w;
      h[4] = (_Float16)p1.x; h[5] = (_Float16)p1.y; h[6] = (_Float16)p1.z; h[7] = (_Float16)p1.w;
      *(half8*)(xh + e) = h;
    } else if (idx < NX + NW) {
      long e = (idx - NX) * 8;
      int row = (int)(e >> 11);
      half8 h;
      if (row < C_) {
        float4 p0 = *(const float4*)(Wm + e);
        float4 p1 = *(const float4*)(Wm + e + 4);
        h[0] = (_Float16)p0.x; h[1] = (_Float16)p0.y; h[2] = (_Float16)p0.z; h[3] = (_Float16)p0.w;
        h[4] = (_Float16)p1.x; h[5] = (_Float16)p1.y; h[6] = (_Float16)p1.z; h[7] = (_Float16)p1.w;
      } else {
        h = (half8)(_Float16)0.f;
      }
      *(half8*)(wh + e) = h;
    } else if (idx < NX + NW + NUV) {
      long e = (idx - NX - NW) * 8;
      int j = (int)(e >> 10);
      int k = (int)(e & 1023);
      const float* src = (j & 1) ? v : u;
      int p = j >> 1;
      half8 h;
      #pragma unroll
      for (int t = 0; t < 8; ++t) {
        int kk = k + t;
        h[t] = (kk < C_) ? (_Float16)src[(size_t)p * C_ + kk] : (_Float16)0.f;
      }
      *(half8*)(uvh + e) = h;
    } else {
      long e = (idx - NX - NW - NUV) * 8;
      float4 z = {0.f, 0.f, 0.f, 0.f};
      if (e < B_) {
        *(float4*)(scores + e) = z; *(float4*)(scores + e + 4) = z;
      } else {
        long r = e - B_;
        *(float4*)(rowsum + r) = z; *(float4*)(rowsum + r + 4) = z;
      }
    }
  }
}

// ---------------- main GEMM: preds = xh @ wh^T + bm ----------------
// 128x128 tile, BK=64, double-buffered LDS, counted vmcnt(8): loads for
// tile k+1 stay in flight across the compute of tile k (T3/T4 minimal 2ph).
__global__ __launch_bounds__(256) void gemm1_kernel(
    const _Float16* __restrict__ xh, const _Float16* __restrict__ wh,
    const float* __restrict__ bmv, float* __restrict__ preds,
    _Float16* __restrict__ predsh, float* __restrict__ rowsum)
{
  __shared__ _Float16 sA[2][128 * 64];
  __shared__ _Float16 sB[2][128 * 64];
  const int tid  = threadIdx.x;
  const int lane = tid & 63;
  const int w    = tid >> 6;
  const int wm   = w >> 1, wn = w & 1;
  const int bm0  = blockIdx.x * 128;
  const int bn0  = blockIdx.y * 128;

  f32x4 acc[4][4] = {};

  const _Float16* srcA[4]; const _Float16* srcB[4];
  #pragma unroll
  for (int i = 0; i < 4; ++i) {
    int slot = i * 256 + tid;
    int row  = slot >> 3;
    int cb   = (slot & 7) << 4;
    int scb  = cb ^ ((row & 7) << 4);                 // inverse-swizzled source
    srcA[i] = xh + (size_t)(bm0 + row) * DIN + (scb >> 1);
    srcB[i] = wh + (size_t)(bn0 + row) * DIN + (scb >> 1);
  }
  int aoff[4][2], boff[4][2];
  #pragma unroll
  for (int mi = 0; mi < 4; ++mi) {
    #pragma unroll
    for (int ks = 0; ks < 2; ++ks) {
      int kb = ks * 64 + (lane >> 4) * 16;
      int ra = wm * 64 + mi * 16 + (lane & 15);
      aoff[mi][ks] = ra * 128 + (kb ^ ((ra & 7) << 4));
      int rb = wn * 64 + mi * 16 + (lane & 15);
      boff[mi][ks] = rb * 128 + (kb ^ ((rb & 7) << 4));
    }
  }

  auto stage = [&](int c) {
    #pragma unroll
    for (int i = 0; i < 4; ++i) {
      gload16(srcA[i], &sA[c][(i * 4 + w) * 512]);
      gload16(srcB[i], &sB[c][(i * 4 + w) * 512]);
      srcA[i] += 64; srcB[i] += 64;
    }
  };

  auto compute = [&](int c) {
    const char* bA = (const char*)&sA[c][0];
    const char* bB = (const char*)&sB[c][0];
    #pragma unroll
    for (int ks = 0; ks < 2; ++ks) {
      half8 a[4], b[4];
      #pragma unroll
      for (int mi = 0; mi < 4; ++mi) a[mi] = *(const half8*)(bA + aoff[mi][ks]);
      #pragma unroll
      for (int ni = 0; ni < 4; ++ni) b[ni] = *(const half8*)(bB + boff[ni][ks]);
      #pragma unroll
      for (int mi = 0; mi < 4; ++mi)
        #pragma unroll
        for (int ni = 0; ni < 4; ++ni)
          acc[mi][ni] = __builtin_amdgcn_mfma_f32_16x16x32_f16(a[mi], b[ni], acc[mi][ni], 0, 0, 0);
    }
  };

  const int NT = DIN / 64;   // 32
  stage(0);
  #pragma unroll 1
  for (int kt = 0; kt < NT; kt += 2) {
    // --- sub-iter A: compute buf0, stage buf1 ---
    stage(1);
    asm volatile("s_waitcnt vmcnt(8)" ::: "memory");   // buf0's 8 loads done
    __builtin_amdgcn_s_barrier();
    asm volatile("" ::: "memory");
    compute(0);
    __builtin_amdgcn_s_barrier();
    asm volatile("" ::: "memory");
    // --- sub-iter B: compute buf1, stage buf0 (skip stage on last tile) ---
    if (kt + 2 < NT) {
      stage(0);
      asm volatile("s_waitcnt vmcnt(8)" ::: "memory");
    } else {
      asm volatile("s_waitcnt vmcnt(0)" ::: "memory");
    }
    __builtin_amdgcn_s_barrier();
    asm volatile("" ::: "memory");
    compute(1);
    __builtin_amdgcn_s_barrier();
    asm volatile("" ::: "memory");
  }

  // epilogue: bias add, f32 store to d_out, f16 store for gating, rowsum partials
  float rp[4][4] = {};
  #pragma unroll
  for (int mi = 0; mi < 4; ++mi) {
    #pragma unroll
    for (int ni = 0; ni < 4; ++ni) {
      f32x4 d = acc[mi][ni];
      int gc = bn0 + wn * 64 + ni * 16 + (lane & 15);
      float bias = (gc < C_) ? bmv[gc] : 0.f;
      #pragma unroll
      for (int j = 0; j < 4; ++j) {
        int gr = bm0 + wm * 64 + mi * 16 + (lane >> 4) * 4 + j;
        float val = d[j] + bias;
        predsh[(size_t)gr * CP + gc] = (_Float16)val;
        if (gc < C_) preds[(size_t)gr * C_ + gc] = val;
        rp[mi][j] += val;
      }
    }
  }
  #pragma unroll
  for (int mi = 0; mi < 4; ++mi) {
    #pragma unroll
    for (int j = 0; j < 4; ++j) {
      float s = rp[mi][j];
      s += __shfl_xor(s, 1); s += __shfl_xor(s, 2);
      s += __shfl_xor(s, 4); s += __shfl_xor(s, 8);
      if ((lane & 15) == 0) {
        int gr = bm0 + wm * 64 + mi * 16 + (lane >> 4) * 4 + j;
        atomicAdd(&rowsum[gr], s);
      }
    }
  }
}

// ---------------- gating GEMM: scores partials ----------------
// BM=64, BN=128 (grid 128x4 = 512 blocks -> 2 blocks/CU instead of 1),
// same dbuf + counted-vmcnt structure. 6 loads/stage -> vmcnt(6).
__global__ __launch_bounds__(256) void gemm2_kernel(
    const _Float16* __restrict__ predsh, const _Float16* __restrict__ uvh,
    const float* __restrict__ wv, float* __restrict__ scores)
{
  __shared__ _Float16 sA[2][64 * 64];
  __shared__ _Float16 sB[2][128 * 64];
  const int tid  = threadIdx.x;
  const int lane = tid & 63;
  const int w    = tid >> 6;
  const int wm   = w >> 1, wn = w & 1;   // 2x2 wave grid: wave owns 32x64
  const int bm0  = blockIdx.x * 64;
  const int bn0  = blockIdx.y * 128;

  f32x4 acc[2][4] = {};

  const _Float16* srcA[2]; const _Float16* srcB[4];
  #pragma unroll
  for (int i = 0; i < 2; ++i) {
    int slot = i * 256 + tid;
    int row  = slot >> 3;
    int cb   = (slot & 7) << 4;
    int scb  = cb ^ ((row & 7) << 4);
    srcA[i] = predsh + (size_t)(bm0 + row) * CP + (scb >> 1);
  }
  #pragma unroll
  for (int i = 0; i < 4; ++i) {
    int slot = i * 256 + tid;
    int row  = slot >> 3;
    int cb   = (slot & 7) << 4;
    int scb  = cb ^ ((row & 7) << 4);
    srcB[i] = uvh + (size_t)(bn0 + row) * CP + (scb >> 1);
  }
  int aoff[2][2], boff[4][2];
  #pragma unroll
  for (int ks = 0; ks < 2; ++ks) {
    int kb = ks * 64 + (lane >> 4) * 16;
    #pragma unroll
    for (int mi = 0; mi < 2; ++mi) {
      int ra = wm * 32 + mi * 16 + (lane & 15);
      aoff[mi][ks] = ra * 128 + (kb ^ ((ra & 7) << 4));
    }
    #pragma unroll
    for (int ni = 0; ni < 4; ++ni) {
      int rb = wn * 64 + ni * 16 + (lane & 15);
      boff[ni][ks] = rb * 128 + (kb ^ ((rb & 7) << 4));
    }
  }

  auto stage = [&](int c) {
    #pragma unroll
    for (int i = 0; i < 2; ++i) {
      gload16(srcA[i], &sA[c][(i * 4 + w) * 512]);
      srcA[i] += 64;
    }
    #pragma unroll
    for (int i = 0; i < 4; ++i) {
      gload16(srcB[i], &sB[c][(i * 4 + w) * 512]);
      srcB[i] += 64;
    }
  };

  auto compute = [&](int c) {
    const char* bA = (const char*)&sA[c][0];
    const char* bB = (const char*)&sB[c][0];
    #pragma unroll
    for (int ks = 0; ks < 2; ++ks) {
      half8 a[2], b[4];
      #pragma unroll
      for (int mi = 0; mi < 2; ++mi) a[mi] = *(const half8*)(bA + aoff[mi][ks]);
      #pragma unroll
      for (int ni = 0; ni < 4; ++ni) b[ni] = *(const half8*)(bB + boff[ni][ks]);
      #pragma unroll
      for (int mi = 0; mi < 2; ++mi)
        #pragma unroll
        for (int ni = 0; ni < 4; ++ni)
          acc[mi][ni] = __builtin_amdgcn_mfma_f32_16x16x32_f16(a[mi], b[ni], acc[mi][ni], 0, 0, 0);
    }
  };

  const int NT = CP / 64;   // 16
  stage(0);
  #pragma unroll 1
  for (int kt = 0; kt < NT; kt += 2) {
    stage(1);
    asm volatile("s_waitcnt vmcnt(6)" ::: "memory");
    __builtin_amdgcn_s_barrier();
    asm volatile("" ::: "memory");
    compute(0);
    __builtin_amdgcn_s_barrier();
    asm volatile("" ::: "memory");
    if (kt + 2 < NT) {
      stage(0);
      asm volatile("s_waitcnt vmcnt(6)" ::: "memory");
    } else {
      asm volatile("s_waitcnt vmcnt(0)" ::: "memory");
    }
    __builtin_amdgcn_s_barrier();
    asm volatile("" ::: "memory");
    compute(1);
    __builtin_amdgcn_s_barrier();
    asm volatile("" ::: "memory");
  }

  // epilogue: gated = tanh(e_u)*sigmoid(e_v)*w_q ; accumulate per-row score partials
  float sp[2][4] = {};
  #pragma unroll
  for (int mi = 0; mi < 2; ++mi) {
    #pragma unroll
    for (int ni = 0; ni < 4; ++ni) {
      f32x4 d = acc[mi][ni];
      int gc = bn0 + wn * 64 + ni * 16 + (lane & 15);   // 0..511 ; even=u col, odd=v col
      float wq = wv[gc >> 1];
      bool even = ((gc & 1) == 0);
      #pragma unroll
      for (int j = 0; j < 4; ++j) {
        float t  = d[j];
        float pr = __shfl_xor(t, 1);                    // partner column value
        float th = 2.f / (1.f + __expf(-2.f * t)) - 1.f; // tanh
        float sg = 1.f / (1.f + __expf(-pr));            // sigmoid
        sp[mi][j] += even ? (th * sg * wq) : 0.f;
      }
    }
  }
  #pragma unroll
  for (int mi = 0; mi < 2; ++mi) {
    #pragma unroll
    for (int j = 0; j < 4; ++j) {
      float s = sp[mi][j];
      s += __shfl_xor(s, 1); s += __shfl_xor(s, 2);
      s += __shfl_xor(s, 4); s += __shfl_xor(s, 8);
      if ((lane & 15) == 0) {
        int gr = bm0 + wm * 32 + mi * 16 + (lane >> 4) * 4 + j;
        atomicAdd(&scores[gr], s);
      }
    }
  }
}

// ---------------- final: softmax over scores, weighted rowsum ----------------
__global__ __launch_bounds__(1024) void final_kernel(
    const float* __restrict__ scores, const float* __restrict__ rowsum,
    float* __restrict__ out)
{
  __shared__ float red[16], red2[16];
  const int t = threadIdx.x;
  const int lane = t & 63, wid = t >> 6;
  float s[8];
  float m = -3.4e38f;
  #pragma unroll
  for (int i = 0; i < 8; ++i) { s[i] = scores[t + i * 1024]; m = fmaxf(m, s[i]); }
  #pragma unroll
  for (int off = 1; off < 64; off <<= 1) m = fmaxf(m, __shfl_xor(m, off));
  if (lane == 0) red[wid] = m;
  __syncthreads();
  #pragma unroll
  for (int i = 0; i < 16; ++i) m = fmaxf(m, red[i]);
  __syncthreads();

  float se = 0.f, sr = 0.f;
  #pragma unroll
  for (int i = 0; i < 8; ++i) {
    float e = __expf(s[i] - m);
    se += e;
    sr += e * rowsum[t + i * 1024];
  }
  #pragma unroll
  for (int off = 1; off < 64; off <<= 1) { se += __shfl_xor(se, off); sr += __shfl_xor(sr, off); }
  if (lane == 0) { red[wid] = se; red2[wid] = sr; }
  __syncthreads();
  if (t == 0) {
    float tse = 0.f, tsr = 0.f;
    for (int i = 0; i < 16; ++i) { tse += red[i]; tsr += red2[i]; }
    out[0] = tsr / tse;
  }
}

extern "C" void kernel_launch(void* const* d_in, const int* in_sizes, int n_in,
                              void* d_out, int out_size, void* d_ws, size_t ws_size,
                              hipStream_t stream)
{
  const float* x   = (const float*)d_in[0];
  const float* Wm  = (const float*)d_in[1];
  const float* bmv = (const float*)d_in[2];
  const float* u   = (const float*)d_in[3];
  const float* v   = (const float*)d_in[4];
  const float* wv  = (const float*)d_in[5];
  float* out = (float*)d_out;

  if (ws_size < WS_NEED) return;  // fail loudly via validation rather than corrupt

  char* ws = (char*)d_ws;
  _Float16* xh     = (_Float16*)(ws + OFF_XH);
  _Float16* wh     = (_Float16*)(ws + OFF_WH);
  _Float16* uvh    = (_Float16*)(ws + OFF_UVH);
  _Float16* predsh = (_Float16*)(ws + OFF_PH);
  float*    scores = (float*)(ws + OFF_SC);
  float*    rowsum = (float*)(ws + OFF_RS);

  prep_kernel<<<2048, 256, 0, stream>>>(x, Wm, u, v, xh, wh, uvh, scores, rowsum);
  gemm1_kernel<<<dim3(64, 8), 256, 0, stream>>>(xh, wh, bmv, out, predsh, rowsum);
  gemm2_kernel<<<dim3(128, 4), 256, 0, stream>>>(predsh, uvh, wv, scores);
  final_kernel<<<1, 1024, 0, stream>>>(scores, rowsum, out + (size_t)B_ * C_);
}

// Round 3
// 92.934 us; speedup vs baseline: 1.0924x; 1.0286x over previous
//
#include <hip/hip_runtime.h>
#include <hip/hip_fp16.h>

typedef _Float16 half8 __attribute__((ext_vector_type(8)));
typedef float f32x4 __attribute__((ext_vector_type(4)));

#define B_   8192
#define DIN  2048
#define C_   1000
#define CP   1024
#define NP2  512   // u,v interleaved rows

// ---- workspace layout (bytes) ----
static const size_t OFF_WH  = 0;                                   // wh  [1024][2048] f16 (rows>=1000 zero)
static const size_t OFF_UVH = OFF_WH  + (size_t)CP * DIN * 2;      // uvh [512][1024]  f16 (row 2q=u_q, 2q+1=v_q)
static const size_t OFF_PH  = OFF_UVH + (size_t)NP2 * CP * 2;      // predsh [8192][1024] f16
static const size_t OFF_SC  = OFF_PH  + (size_t)B_ * CP * 2;       // scores [8192] f32
static const size_t OFF_RS  = OFF_SC  + (size_t)B_ * 4;            // rowsum [8192] f32
static const size_t WS_NEED = OFF_RS  + (size_t)B_ * 4;

__device__ __forceinline__ void gload16(const void* g, void* l) {
  __builtin_amdgcn_global_load_lds(
      (const __attribute__((address_space(1))) void*)g,
      (__attribute__((address_space(3))) void*)l, 16, 0, 0);
}

// ---------------- prep: f32 -> f16 conversions (Wm, u/v) + zeroing ----------------
__global__ __launch_bounds__(256) void prep_kernel(
    const float* __restrict__ Wm,
    const float* __restrict__ u, const float* __restrict__ v,
    _Float16* __restrict__ wh, _Float16* __restrict__ uvh,
    float* __restrict__ scores, float* __restrict__ rowsum)
{
  const long NW  = (long)CP * DIN / 8;      //   262,144
  const long NUV = (long)NP2 * CP / 8;      //    65,536
  const long NZ  = 2 * (long)B_ / 8;        //     2,048
  const long T   = NW + NUV + NZ;
  for (long idx = (long)blockIdx.x * blockDim.x + threadIdx.x; idx < T;
       idx += (long)gridDim.x * blockDim.x) {
    if (idx < NW) {
      long e = idx * 8;
      int row = (int)(e >> 11);
      half8 h;
      if (row < C_) {
        float4 p0 = *(const float4*)(Wm + e);
        float4 p1 = *(const float4*)(Wm + e + 4);
        h[0] = (_Float16)p0.x; h[1] = (_Float16)p0.y; h[2] = (_Float16)p0.z; h[3] = (_Float16)p0.w;
        h[4] = (_Float16)p1.x; h[5] = (_Float16)p1.y; h[6] = (_Float16)p1.z; h[7] = (_Float16)p1.w;
      } else {
        h = (half8)(_Float16)0.f;
      }
      *(half8*)(wh + e) = h;
    } else if (idx < NW + NUV) {
      long e = (idx - NW) * 8;
      int j = (int)(e >> 10);
      int k = (int)(e & 1023);
      const float* src = (j & 1) ? v : u;
      int p = j >> 1;
      half8 h;
      #pragma unroll
      for (int t = 0; t < 8; ++t) {
        int kk = k + t;
        h[t] = (kk < C_) ? (_Float16)src[(size_t)p * C_ + kk] : (_Float16)0.f;
      }
      *(half8*)(uvh + e) = h;
    } else {
      long e = (idx - NW - NUV) * 8;
      float4 z = {0.f, 0.f, 0.f, 0.f};
      if (e < B_) {
        *(float4*)(scores + e) = z; *(float4*)(scores + e + 4) = z;
      } else {
        long r = e - B_;
        *(float4*)(rowsum + r) = z; *(float4*)(rowsum + r + 4) = z;
      }
    }
  }
}

// ---------------- main GEMM: preds = x @ wh^T + bm ----------------
// 128x128 tile, BK=64, double-buffered LDS.
// A staged straight from f32 x: global_load_dwordx4 -> v_cvt -> swizzled
// ds_write_b128 (T14: loads issued before compute, cvt+write after -> HBM
// latency hides under MFMA). B staged via global_load_lds with counted
// vmcnt(12) (FIFO: B(t)x4 oldest, A(t+1)x8, B(t+1)x4).
__global__ __launch_bounds__(256) void gemm1_kernel(
    const float* __restrict__ x, const _Float16* __restrict__ wh,
    const float* __restrict__ bmv, float* __restrict__ preds,
    _Float16* __restrict__ predsh, float* __restrict__ rowsum)
{
  __shared__ _Float16 sA[2][128 * 64];
  __shared__ _Float16 sB[2][128 * 64];
  const int tid  = threadIdx.x;
  const int lane = tid & 63;
  const int w    = tid >> 6;
  const int wm   = w >> 1, wn = w & 1;
  const int bm0  = blockIdx.x * 128;
  const int bn0  = blockIdx.y * 128;

  f32x4 acc[4][4] = {};

  // A: per-thread slots (identical slot->(row,cb) map as validated kernel)
  const float* srcA[4];
  int dstAoff[4];
  #pragma unroll
  for (int i = 0; i < 4; ++i) {
    int slot = i * 256 + tid;
    int row  = slot >> 3;
    int cb   = (slot & 7) << 4;                        // byte offset in 128B row
    dstAoff[i] = row * 128 + (cb ^ ((row & 7) << 4));  // swizzled write addr
    srcA[i] = x + (size_t)(bm0 + row) * DIN + (slot & 7) * 8;
  }
  // B: pre-swizzled global source, linear gload_lds dest (as validated)
  const _Float16* srcB[4];
  #pragma unroll
  for (int i = 0; i < 4; ++i) {
    int slot = i * 256 + tid;
    int row  = slot >> 3;
    int cb   = (slot & 7) << 4;
    int scb  = cb ^ ((row & 7) << 4);
    srcB[i] = wh + (size_t)(bn0 + row) * DIN + (scb >> 1);
  }
  int aoff[4][2], boff[4][2];
  #pragma unroll
  for (int mi = 0; mi < 4; ++mi) {
    #pragma unroll
    for (int ks = 0; ks < 2; ++ks) {
      int kb = ks * 64 + (lane >> 4) * 16;
      int ra = wm * 64 + mi * 16 + (lane & 15);
      aoff[mi][ks] = ra * 128 + (kb ^ ((ra & 7) << 4));
      int rb = wn * 64 + mi * 16 + (lane & 15);
      boff[mi][ks] = rb * 128 + (kb ^ ((rb & 7) << 4));
    }
  }

  float4 ra[4][2];
  auto loadA = [&]() {
    #pragma unroll
    for (int i = 0; i < 4; ++i) {
      ra[i][0] = *(const float4*)(srcA[i]);
      ra[i][1] = *(const float4*)(srcA[i] + 4);
      srcA[i] += 64;
    }
  };
  auto writeA = [&](int c) {
    #pragma unroll
    for (int i = 0; i < 4; ++i) {
      half8 h;
      h[0] = (_Float16)ra[i][0].x; h[1] = (_Float16)ra[i][0].y;
      h[2] = (_Float16)ra[i][0].z; h[3] = (_Float16)ra[i][0].w;
      h[4] = (_Float16)ra[i][1].x; h[5] = (_Float16)ra[i][1].y;
      h[6] = (_Float16)ra[i][1].z; h[7] = (_Float16)ra[i][1].w;
      *(half8*)((char*)&sA[c][0] + dstAoff[i]) = h;
    }
  };
  auto stageB = [&](int c) {
    #pragma unroll
    for (int i = 0; i < 4; ++i) {
      gload16(srcB[i], &sB[c][(i * 4 + w) * 512]);
      srcB[i] += 64;
    }
  };
  auto compute = [&](int c) {
    const char* bA = (const char*)&sA[c][0];
    const char* bB = (const char*)&sB[c][0];
    #pragma unroll
    for (int ks = 0; ks < 2; ++ks) {
      half8 a[4], b[4];
      #pragma unroll
      for (int mi = 0; mi < 4; ++mi) a[mi] = *(const half8*)(bA + aoff[mi][ks]);
      #pragma unroll
      for (int ni = 0; ni < 4; ++ni) b[ni] = *(const half8*)(bB + boff[ni][ks]);
      #pragma unroll
      for (int mi = 0; mi < 4; ++mi)
        #pragma unroll
        for (int ni = 0; ni < 4; ++ni)
          acc[mi][ni] = __builtin_amdgcn_mfma_f32_16x16x32_f16(a[mi], b[ni], acc[mi][ni], 0, 0, 0);
    }
  };

  const int NT = DIN / 64;   // 32

  // prologue: stage tile 0 into buf 0
  loadA();
  stageB(0);
  writeA(0);
  asm volatile("s_waitcnt vmcnt(0) lgkmcnt(0)" ::: "memory");
  __builtin_amdgcn_s_barrier();

  #pragma unroll 1
  for (int t = 0; t < NT - 1; ++t) {
    const int c = t & 1;
    loadA();                 // A(t+1) -> regs          (+8 vm)
    stageB(c ^ 1);           // B(t+1) -> LDS buf c^1   (+4 vm)
    asm volatile("s_waitcnt vmcnt(12)" ::: "memory");   // drain B(t)
    __builtin_amdgcn_s_barrier();
    compute(c);
    writeA(c ^ 1);           // cvt + swizzled ds_write (compiler waits A regs)
    asm volatile("s_waitcnt lgkmcnt(0)" ::: "memory");
    __builtin_amdgcn_s_barrier();
  }
  // tail: compute last tile
  asm volatile("s_waitcnt vmcnt(0)" ::: "memory");
  __builtin_amdgcn_s_barrier();
  compute((NT - 1) & 1);

  // epilogue: bias add, f32 store to d_out, f16 store for gating, rowsum partials
  float rp[4][4] = {};
  #pragma unroll
  for (int mi = 0; mi < 4; ++mi) {
    #pragma unroll
    for (int ni = 0; ni < 4; ++ni) {
      f32x4 d = acc[mi][ni];
      int gc = bn0 + wn * 64 + ni * 16 + (lane & 15);
      float bias = (gc < C_) ? bmv[gc] : 0.f;
      #pragma unroll
      for (int j = 0; j < 4; ++j) {
        int gr = bm0 + wm * 64 + mi * 16 + (lane >> 4) * 4 + j;
        float val = d[j] + bias;
        predsh[(size_t)gr * CP + gc] = (_Float16)val;
        if (gc < C_) preds[(size_t)gr * C_ + gc] = val;
        rp[mi][j] += val;
      }
    }
  }
  #pragma unroll
  for (int mi = 0; mi < 4; ++mi) {
    #pragma unroll
    for (int j = 0; j < 4; ++j) {
      float s = rp[mi][j];
      s += __shfl_xor(s, 1); s += __shfl_xor(s, 2);
      s += __shfl_xor(s, 4); s += __shfl_xor(s, 8);
      if ((lane & 15) == 0) {
        int gr = bm0 + wm * 64 + mi * 16 + (lane >> 4) * 4 + j;
        atomicAdd(&rowsum[gr], s);
      }
    }
  }
}

// ---------------- gating GEMM: scores partials ----------------
// BM=64, BN=128 (grid 128x4 = 512 blocks -> 2 blocks/CU),
// dbuf + counted-vmcnt structure. 6 loads/stage -> vmcnt(6).
__global__ __launch_bounds__(256) void gemm2_kernel(
    const _Float16* __restrict__ predsh, const _Float16* __restrict__ uvh,
    const float* __restrict__ wv, float* __restrict__ scores)
{
  __shared__ _Float16 sA[2][64 * 64];
  __shared__ _Float16 sB[2][128 * 64];
  const int tid  = threadIdx.x;
  const int lane = tid & 63;
  const int w    = tid >> 6;
  const int wm   = w >> 1, wn = w & 1;   // 2x2 wave grid: wave owns 32x64
  const int bm0  = blockIdx.x * 64;
  const int bn0  = blockIdx.y * 128;

  f32x4 acc[2][4] = {};

  const _Float16* srcA[2]; const _Float16* srcB[4];
  #pragma unroll
  for (int i = 0; i < 2; ++i) {
    int slot = i * 256 + tid;
    int row  = slot >> 3;
    int cb   = (slot & 7) << 4;
    int scb  = cb ^ ((row & 7) << 4);
    srcA[i] = predsh + (size_t)(bm0 + row) * CP + (scb >> 1);
  }
  #pragma unroll
  for (int i = 0; i < 4; ++i) {
    int slot = i * 256 + tid;
    int row  = slot >> 3;
    int cb   = (slot & 7) << 4;
    int scb  = cb ^ ((row & 7) << 4);
    srcB[i] = uvh + (size_t)(bn0 + row) * CP + (scb >> 1);
  }
  int aoff[2][2], boff[4][2];
  #pragma unroll
  for (int ks = 0; ks < 2; ++ks) {
    int kb = ks * 64 + (lane >> 4) * 16;
    #pragma unroll
    for (int mi = 0; mi < 2; ++mi) {
      int ra = wm * 32 + mi * 16 + (lane & 15);
      aoff[mi][ks] = ra * 128 + (kb ^ ((ra & 7) << 4));
    }
    #pragma unroll
    for (int ni = 0; ni < 4; ++ni) {
      int rb = wn * 64 + ni * 16 + (lane & 15);
      boff[ni][ks] = rb * 128 + (kb ^ ((rb & 7) << 4));
    }
  }

  auto stage = [&](int c) {
    #pragma unroll
    for (int i = 0; i < 2; ++i) {
      gload16(srcA[i], &sA[c][(i * 4 + w) * 512]);
      srcA[i] += 64;
    }
    #pragma unroll
    for (int i = 0; i < 4; ++i) {
      gload16(srcB[i], &sB[c][(i * 4 + w) * 512]);
      srcB[i] += 64;
    }
  };

  auto compute = [&](int c) {
    const char* bA = (const char*)&sA[c][0];
    const char* bB = (const char*)&sB[c][0];
    #pragma unroll
    for (int ks = 0; ks < 2; ++ks) {
      half8 a[2], b[4];
      #pragma unroll
      for (int mi = 0; mi < 2; ++mi) a[mi] = *(const half8*)(bA + aoff[mi][ks]);
      #pragma unroll
      for (int ni = 0; ni < 4; ++ni) b[ni] = *(const half8*)(bB + boff[ni][ks]);
      #pragma unroll
      for (int mi = 0; mi < 2; ++mi)
        #pragma unroll
        for (int ni = 0; ni < 4; ++ni)
          acc[mi][ni] = __builtin_amdgcn_mfma_f32_16x16x32_f16(a[mi], b[ni], acc[mi][ni], 0, 0, 0);
    }
  };

  const int NT = CP / 64;   // 16
  stage(0);
  #pragma unroll 1
  for (int kt = 0; kt < NT; kt += 2) {
    stage(1);
    asm volatile("s_waitcnt vmcnt(6)" ::: "memory");
    __builtin_amdgcn_s_barrier();
    compute(0);
    __builtin_amdgcn_s_barrier();
    if (kt + 2 < NT) {
      stage(0);
      asm volatile("s_waitcnt vmcnt(6)" ::: "memory");
    } else {
      asm volatile("s_waitcnt vmcnt(0)" ::: "memory");
    }
    __builtin_amdgcn_s_barrier();
    compute(1);
    __builtin_amdgcn_s_barrier();
  }

  // epilogue: gated = tanh(e_u)*sigmoid(e_v)*w_q ; accumulate per-row score partials
  float sp[2][4] = {};
  #pragma unroll
  for (int mi = 0; mi < 2; ++mi) {
    #pragma unroll
    for (int ni = 0; ni < 4; ++ni) {
      f32x4 d = acc[mi][ni];
      int gc = bn0 + wn * 64 + ni * 16 + (lane & 15);   // even=u col, odd=v col
      float wq = wv[gc >> 1];
      bool even = ((gc & 1) == 0);
      #pragma unroll
      for (int j = 0; j < 4; ++j) {
        float t  = d[j];
        float pr = __shfl_xor(t, 1);                    // partner column value
        float th = 2.f / (1.f + __expf(-2.f * t)) - 1.f; // tanh
        float sg = 1.f / (1.f + __expf(-pr));            // sigmoid
        sp[mi][j] += even ? (th * sg * wq) : 0.f;
      }
    }
  }
  #pragma unroll
  for (int mi = 0; mi < 2; ++mi) {
    #pragma unroll
    for (int j = 0; j < 4; ++j) {
      float s = sp[mi][j];
      s += __shfl_xor(s, 1); s += __shfl_xor(s, 2);
      s += __shfl_xor(s, 4); s += __shfl_xor(s, 8);
      if ((lane & 15) == 0) {
        int gr = bm0 + wm * 32 + mi * 16 + (lane >> 4) * 4 + j;
        atomicAdd(&scores[gr], s);
      }
    }
  }
}

// ---------------- final: softmax over scores, weighted rowsum ----------------
__global__ __launch_bounds__(1024) void final_kernel(
    const float* __restrict__ scores, const float* __restrict__ rowsum,
    float* __restrict__ out)
{
  __shared__ float red[16], red2[16];
  const int t = threadIdx.x;
  const int lane = t & 63, wid = t >> 6;
  float s[8];
  float m = -3.4e38f;
  #pragma unroll
  for (int i = 0; i < 8; ++i) { s[i] = scores[t + i * 1024]; m = fmaxf(m, s[i]); }
  #pragma unroll
  for (int off = 1; off < 64; off <<= 1) m = fmaxf(m, __shfl_xor(m, off));
  if (lane == 0) red[wid] = m;
  __syncthreads();
  #pragma unroll
  for (int i = 0; i < 16; ++i) m = fmaxf(m, red[i]);
  __syncthreads();

  float se = 0.f, sr = 0.f;
  #pragma unroll
  for (int i = 0; i < 8; ++i) {
    float e = __expf(s[i] - m);
    se += e;
    sr += e * rowsum[t + i * 1024];
  }
  #pragma unroll
  for (int off = 1; off < 64; off <<= 1) { se += __shfl_xor(se, off); sr += __shfl_xor(sr, off); }
  if (lane == 0) { red[wid] = se; red2[wid] = sr; }
  __syncthreads();
  if (t == 0) {
    float tse = 0.f, tsr = 0.f;
    for (int i = 0; i < 16; ++i) { tse += red[i]; tsr += red2[i]; }
    out[0] = tsr / tse;
  }
}

extern "C" void kernel_launch(void* const* d_in, const int* in_sizes, int n_in,
                              void* d_out, int out_size, void* d_ws, size_t ws_size,
                              hipStream_t stream)
{
  const float* x   = (const float*)d_in[0];
  const float* Wm  = (const float*)d_in[1];
  const float* bmv = (const float*)d_in[2];
  const float* u   = (const float*)d_in[3];
  const float* v   = (const float*)d_in[4];
  const float* wv  = (const float*)d_in[5];
  float* out = (float*)d_out;

  if (ws_size < WS_NEED) return;

  char* ws = (char*)d_ws;
  _Float16* wh     = (_Float16*)(ws + OFF_WH);
  _Float16* uvh    = (_Float16*)(ws + OFF_UVH);
  _Float16* predsh = (_Float16*)(ws + OFF_PH);
  float*    scores = (float*)(ws + OFF_SC);
  float*    rowsum = (float*)(ws + OFF_RS);

  prep_kernel<<<1288, 256, 0, stream>>>(Wm, u, v, wh, uvh, scores, rowsum);
  gemm1_kernel<<<dim3(64, 8), 256, 0, stream>>>(x, wh, bmv, out, predsh, rowsum);
  gemm2_kernel<<<dim3(128, 4), 256, 0, stream>>>(predsh, uvh, wv, scores);
  final_kernel<<<1, 1024, 0, stream>>>(scores, rowsum, out + (size_t)B_ * C_);
}